// Round 1
// baseline (1470.513 us; speedup 1.0000x reference)
//
#include <hip/hip_runtime.h>
#include <hip/hip_bf16.h>

typedef __bf16 bf16x8 __attribute__((ext_vector_type(8)));
typedef float f32x4 __attribute__((ext_vector_type(4)));
typedef unsigned short u16x4 __attribute__((ext_vector_type(4)));

#define N_TOKENS 32768
#define N_CODES 4096
#define DIM 1280
#define NCB 32  // column blocks = 4096/128

__device__ __forceinline__ unsigned short f2bf(float f) {
    unsigned u = __float_as_uint(f);
    return (unsigned short)((u + 0x7FFFu + ((u >> 16) & 1u)) >> 16);
}
__device__ __forceinline__ float bf2f(unsigned short h) {
    return __uint_as_float(((unsigned)h) << 16);
}

// ---------------------------------------------------------------------------
// Kernel 1: split-bf16 GEMM (X[32768,1280] x E[4096,1280]^T) with fused
// per-row argmax over each 128-col block. Writes per-(colblock,row) best key.
// Key = monotone-encoded fp32 score (hi 32) | (4095 - col) (lo 32) so that
// u64 max == (max score, tie -> lowest index), matching jnp.argmax.
// ---------------------------------------------------------------------------
__global__ __launch_bounds__(256) void gemm_argmax_kernel(
    const float* __restrict__ X, const float* __restrict__ E,
    unsigned long long* __restrict__ pkeys)
{
    __shared__ unsigned short As_hi[128 * 32], As_lo[128 * 32];
    __shared__ unsigned short Bs_hi[128 * 32], Bs_lo[128 * 32];
    __shared__ unsigned long long lkeys[128];

    int bid = blockIdx.x;
    // bijective XCD swizzle: 8192 blocks over 8 XCDs
    int swz = (bid & 7) * 1024 + (bid >> 3);
    int rb = swz >> 5, cb = swz & 31;
    int row0 = rb << 7, col0 = cb << 7;

    int tid = threadIdx.x;
    int wid = tid >> 6, lane = tid & 63;
    int wm = wid >> 1, wn = wid & 1;
    int lr = lane & 15, g = lane >> 4;

    f32x4 acc[4][4] = {};

    for (int kt = 0; kt < DIM / 32; ++kt) {
        int k0 = kt << 5;
        __syncthreads();
        // stage 128x32 fp32 tiles of A and B, convert to bf16 hi/lo, swizzled LDS
        #pragma unroll
        for (int i = 0; i < 4; ++i) {
            int flat = tid + (i << 8);          // 0..1023
            int r = flat >> 3, c4 = flat & 7;   // row, float4-column
            const float4 va = *(const float4*)(X + (size_t)(row0 + r) * DIM + k0 + (c4 << 2));
            const float4 vb = *(const float4*)(E + (size_t)(col0 + r) * DIM + k0 + (c4 << 2));
            // swizzle: 16B chunk index ^= (row>>1)&3  (rows are 64B = 4 chunks)
            int base = (r << 5) + (((c4 >> 1) ^ ((r >> 1) & 3)) << 3) + ((c4 & 1) << 2);
            const float fa[4] = {va.x, va.y, va.z, va.w};
            const float fb[4] = {vb.x, vb.y, vb.z, vb.w};
            u16x4 ha, la, hb, lb;
            #pragma unroll
            for (int j = 0; j < 4; ++j) {
                unsigned short h = f2bf(fa[j]);
                ha[j] = h; la[j] = f2bf(fa[j] - bf2f(h));
                unsigned short h2 = f2bf(fb[j]);
                hb[j] = h2; lb[j] = f2bf(fb[j] - bf2f(h2));
            }
            *(u16x4*)&As_hi[base] = ha; *(u16x4*)&As_lo[base] = la;
            *(u16x4*)&Bs_hi[base] = hb; *(u16x4*)&Bs_lo[base] = lb;
        }
        __syncthreads();

        // fragment loads: lane holds 8 contiguous k-elems of row (l&15)+16m,
        // k-chunk g = l>>4  (A and B^T symmetric for NT GEMM)
        bf16x8 ah[4], al[4], bh[4], bl[4];
        #pragma unroll
        for (int m = 0; m < 4; ++m) {
            int row = (wm << 6) + (m << 4) + lr;
            int off = (row << 5) + ((g ^ ((row >> 1) & 3)) << 3);
            ah[m] = *(const bf16x8*)&As_hi[off];
            al[m] = *(const bf16x8*)&As_lo[off];
        }
        #pragma unroll
        for (int n = 0; n < 4; ++n) {
            int row = (wn << 6) + (n << 4) + lr;
            int off = (row << 5) + ((g ^ ((row >> 1) & 3)) << 3);
            bh[n] = *(const bf16x8*)&Bs_hi[off];
            bl[n] = *(const bf16x8*)&Bs_lo[off];
        }
        // 3-pass split: hh + hl + lh accumulate into the same acc
        #pragma unroll
        for (int m = 0; m < 4; ++m)
            #pragma unroll
            for (int n = 0; n < 4; ++n) {
                acc[m][n] = __builtin_amdgcn_mfma_f32_16x16x32_bf16(ah[m], bh[n], acc[m][n], 0, 0, 0);
                acc[m][n] = __builtin_amdgcn_mfma_f32_16x16x32_bf16(ah[m], bl[n], acc[m][n], 0, 0, 0);
                acc[m][n] = __builtin_amdgcn_mfma_f32_16x16x32_bf16(al[m], bh[n], acc[m][n], 0, 0, 0);
            }
    }

    // epilogue: C/D layout col = lane&15, row = (lane>>4)*4 + reg
    unsigned long long bestk[4][4];
    #pragma unroll
    for (int m = 0; m < 4; ++m) {
        #pragma unroll
        for (int r = 0; r < 4; ++r) {
            unsigned long long best = 0;
            #pragma unroll
            for (int n = 0; n < 4; ++n) {
                float s = acc[m][n][r];  // dot(x,e): monotone-equivalent to dist
                int col = col0 + (wn << 6) + (n << 4) + lr;
                unsigned u = __float_as_uint(s);
                u = (u & 0x80000000u) ? ~u : (u | 0x80000000u);
                unsigned long long key =
                    ((unsigned long long)u << 32) | (unsigned)(N_CODES - 1 - col);
                if (key > best) best = key;
            }
            #pragma unroll
            for (int d = 1; d < 16; d <<= 1) {   // reduce across the 16 cols
                unsigned long long o = __shfl_xor(best, d);
                if (o > best) best = o;
            }
            bestk[m][r] = best;
        }
    }
    __syncthreads();
    if (wn == 0 && lr == 0) {
        #pragma unroll
        for (int m = 0; m < 4; ++m)
            #pragma unroll
            for (int r = 0; r < 4; ++r)
                lkeys[(wm << 6) + (m << 4) + (g << 2) + r] = bestk[m][r];
    }
    __syncthreads();
    if (wn == 1 && lr == 0) {
        #pragma unroll
        for (int m = 0; m < 4; ++m)
            #pragma unroll
            for (int r = 0; r < 4; ++r) {
                int rl = (wm << 6) + (m << 4) + (g << 2) + r;
                unsigned long long b = bestk[m][r], o = lkeys[rl];
                if (o > b) b = o;
                pkeys[(size_t)cb * N_TOKENS + row0 + rl] = b;
            }
    }
}

// ---------------------------------------------------------------------------
// Kernel 2: exact fp64 refinement. One wave per token: take the 32 block
// winners, rescore every candidate within 1e-5 of the max with 2*x.e - e.e
// in double, pick max (tie -> lowest index).
// ---------------------------------------------------------------------------
__global__ __launch_bounds__(64) void refine_kernel(
    const float* __restrict__ X, const float* __restrict__ E,
    const unsigned long long* __restrict__ pkeys, int* __restrict__ idx_out)
{
    int token = blockIdx.x;
    int lane = threadIdx.x;
    unsigned long long k = 0;
    if (lane < NCB) k = pkeys[(size_t)lane * N_TOKENS + token];
    unsigned long long m = k;
    #pragma unroll
    for (int d = 1; d < 64; d <<= 1) {
        unsigned long long o = __shfl_xor(m, d);
        if (o > m) m = o;
    }
    unsigned um = (unsigned)(m >> 32);
    unsigned uk = (unsigned)(k >> 32);
    float smax = __uint_as_float((um & 0x80000000u) ? (um & 0x7FFFFFFFu) : ~um);
    float sl   = __uint_as_float((uk & 0x80000000u) ? (uk & 0x7FFFFFFFu) : ~uk);
    bool cand = (lane < NCB) && (sl >= smax - 1e-5f);
    unsigned long long ball = __ballot(cand);
    double best_s = -1.0e300;
    int best_i = 0x7FFFFFFF;
    const float* x = X + (size_t)token * DIM;
    while (ball) {
        int src = __ffsll((unsigned long long)ball) - 1;
        ball &= ball - 1;
        unsigned long long ck = __shfl(k, src);
        int cidx = (N_CODES - 1) - (int)(ck & 0xFFFFFFFFull);
        const float* e = E + (size_t)cidx * DIM;
        double d = 0.0, ee = 0.0;
        for (int i = lane; i < DIM; i += 64) {
            double ev = (double)e[i];
            d += (double)x[i] * ev;
            ee += ev * ev;
        }
        #pragma unroll
        for (int dd = 1; dd < 64; dd <<= 1) {
            d += __shfl_xor(d, dd);
            ee += __shfl_xor(ee, dd);
        }
        double sc = 2.0 * d - ee;
        if (sc > best_s || (sc == best_s && cidx < best_i)) { best_s = sc; best_i = cidx; }
    }
    if (lane == 0) idx_out[token] = best_i;
}

// ---------------------------------------------------------------------------
// Kernel 3: gather quantized = embed[idx] (exact fp32 copy), per-token
// ||x-q||^2 partial, and index-as-float output. 320 threads = DIM/4.
// ---------------------------------------------------------------------------
__global__ __launch_bounds__(320) void gather_kernel(
    const float* __restrict__ X, const float* __restrict__ E,
    const int* __restrict__ idx_in, float* __restrict__ outq,
    float* __restrict__ outidx, float* __restrict__ sums)
{
    int token = blockIdx.x;
    int t = threadIdx.x;
    int idx = idx_in[token];
    const float4* e4 = (const float4*)(E + (size_t)idx * DIM);
    const float4* x4 = (const float4*)(X + (size_t)token * DIM);
    float4* o4 = (float4*)(outq + (size_t)token * DIM);
    float4 q = e4[t];
    float4 xv = x4[t];
    o4[t] = q;
    float dx = xv.x - q.x, dy = xv.y - q.y, dz = xv.z - q.z, dw = xv.w - q.w;
    float local = dx * dx + dy * dy + dz * dz + dw * dw;
    #pragma unroll
    for (int d = 1; d < 64; d <<= 1) local += __shfl_xor(local, d);
    __shared__ float wsum[5];
    int lane = t & 63, w = t >> 6;
    if (lane == 0) wsum[w] = local;
    __syncthreads();
    if (t == 0) {
        sums[token] = wsum[0] + wsum[1] + wsum[2] + wsum[3] + wsum[4];
        outidx[token] = (float)idx;
    }
}

// ---------------------------------------------------------------------------
// Kernel 4: deterministic final loss reduction (fixed tree).
// ---------------------------------------------------------------------------
__global__ __launch_bounds__(256) void loss_kernel(
    const float* __restrict__ sums, float* __restrict__ out_loss)
{
    __shared__ double red[256];
    int t = threadIdx.x;
    double s = 0.0;
    for (int i = t; i < N_TOKENS; i += 256) s += (double)sums[i];
    red[t] = s;
    __syncthreads();
    for (int off = 128; off > 0; off >>= 1) {
        if (t < off) red[t] += red[t + off];
        __syncthreads();
    }
    if (t == 0) out_loss[0] = (float)(red[0] / (double)((size_t)N_TOKENS * DIM));
}

extern "C" void kernel_launch(void* const* d_in, const int* in_sizes, int n_in,
                              void* d_out, int out_size, void* d_ws, size_t ws_size,
                              hipStream_t stream)
{
    const float* X = (const float*)d_in[0];   // (32768, 1280) fp32, L2-normalized
    const float* E = (const float*)d_in[1];   // (4096, 1280) fp32, L2-normalized

    float* outq = (float*)d_out;                       // (32768,1280)
    float* outidx = outq + (size_t)N_TOKENS * DIM;     // (32768,) as float
    float* outloss = outidx + N_TOKENS;                // scalar

    // workspace: pkeys 8 MB | idx 128 KB | sums 128 KB (all rewritten per call)
    unsigned long long* pkeys = (unsigned long long*)d_ws;
    int* idx_ws = (int*)((char*)d_ws + (size_t)NCB * N_TOKENS * sizeof(unsigned long long));
    float* sums = (float*)((char*)idx_ws + (size_t)N_TOKENS * sizeof(int));

    gemm_argmax_kernel<<<dim3(8192), dim3(256), 0, stream>>>(X, E, pkeys);
    refine_kernel<<<dim3(N_TOKENS), dim3(64), 0, stream>>>(X, E, pkeys, idx_ws);
    gather_kernel<<<dim3(N_TOKENS), dim3(320), 0, stream>>>(X, E, idx_ws, outq, outidx, sums);
    loss_kernel<<<dim3(1), dim3(256), 0, stream>>>(sums, outloss);
}

// Round 2
// 895.371 us; speedup vs baseline: 1.6423x; 1.6423x over previous
//
#include <hip/hip_runtime.h>
#include <hip/hip_bf16.h>

typedef __bf16 bf16x8 __attribute__((ext_vector_type(8)));
typedef float f32x4 __attribute__((ext_vector_type(4)));

#define N_TOKENS 32768
#define N_CODES 4096
#define DIM 1280
#define NCB 32  // column blocks = 4096/128

// ---------------------------------------------------------------------------
// Kernel 1: single-pass bf16 GEMM (X[32768,1280] x E[4096,1280]^T) with fused
// per-row TOP-2 argmax over each 128-col block.
// Key (u32) = monotone fp32 score, low 7 mantissa bits replaced by (127-cib)
// so u32-max == (max score, tie -> lowest col). Top-2 per block guarantees the
// true argmax survives single-flip bf16 noise; fp64 refine decides exactly.
// bf16 conversion is TRUNCATION (bit-shift), packed 2 floats -> 1 u32:
// random error sigma ~4.5e-5 (same as RNE), systematic -0.4%*score (uniform
// shrink, argmax-safe) -- covered by refine threshold 2e-3 (~40 sigma).
// ---------------------------------------------------------------------------
__global__ __launch_bounds__(256) void gemm_argmax_kernel(
    const float* __restrict__ X, const float* __restrict__ E,
    unsigned* __restrict__ pkeys)
{
    __shared__ unsigned short As[128 * 32], Bs[128 * 32];
    __shared__ unsigned lk[128 * 2];

    int bid = blockIdx.x;
    // bijective XCD swizzle: 8192 blocks over 8 XCDs
    int swz = (bid & 7) * 1024 + (bid >> 3);
    int rb = swz >> 5, cb = swz & 31;
    int row0 = rb << 7, col0 = cb << 7;

    int tid = threadIdx.x;
    int wid = tid >> 6, lane = tid & 63;
    int wm = wid >> 1, wn = wid & 1;
    int lr = lane & 15, g = lane >> 4;

    f32x4 acc[4][4] = {};

    for (int kt = 0; kt < DIM / 32; ++kt) {
        int k0 = kt << 5;
        __syncthreads();
        // stage 128x32 fp32 tiles -> truncated bf16, swizzled LDS
        #pragma unroll
        for (int i = 0; i < 4; ++i) {
            int flat = tid + (i << 8);          // 0..1023
            int r = flat >> 3, c4 = flat & 7;   // row, float4-column
            const float4 va = *(const float4*)(X + (size_t)(row0 + r) * DIM + k0 + (c4 << 2));
            const float4 vb = *(const float4*)(E + (size_t)(col0 + r) * DIM + k0 + (c4 << 2));
            // swizzle: 16B chunk index ^= (row>>1)&3  (rows are 64B = 4 chunks)
            int base = (r << 5) + (((c4 >> 1) ^ ((r >> 1) & 3)) << 3) + ((c4 & 1) << 2);
            uint2 pa, pb;
            pa.x = (__float_as_uint(va.y) & 0xFFFF0000u) | (__float_as_uint(va.x) >> 16);
            pa.y = (__float_as_uint(va.w) & 0xFFFF0000u) | (__float_as_uint(va.z) >> 16);
            pb.x = (__float_as_uint(vb.y) & 0xFFFF0000u) | (__float_as_uint(vb.x) >> 16);
            pb.y = (__float_as_uint(vb.w) & 0xFFFF0000u) | (__float_as_uint(vb.z) >> 16);
            *(uint2*)&As[base] = pa;
            *(uint2*)&Bs[base] = pb;
        }
        __syncthreads();

        bf16x8 a[4], b[4];
        #pragma unroll
        for (int m = 0; m < 4; ++m) {
            int row = (wm << 6) + (m << 4) + lr;
            int off = (row << 5) + ((g ^ ((row >> 1) & 3)) << 3);
            a[m] = *(const bf16x8*)&As[off];
        }
        #pragma unroll
        for (int n = 0; n < 4; ++n) {
            int row = (wn << 6) + (n << 4) + lr;
            int off = (row << 5) + ((g ^ ((row >> 1) & 3)) << 3);
            b[n] = *(const bf16x8*)&Bs[off];
        }
        #pragma unroll
        for (int m = 0; m < 4; ++m)
            #pragma unroll
            for (int n = 0; n < 4; ++n)
                acc[m][n] = __builtin_amdgcn_mfma_f32_16x16x32_bf16(a[m], b[n], acc[m][n], 0, 0, 0);
    }

    // epilogue: C/D layout col = lane&15, row = (lane>>4)*4 + reg
    unsigned k1[4][4], k2[4][4];
    #pragma unroll
    for (int m = 0; m < 4; ++m) {
        #pragma unroll
        for (int r = 0; r < 4; ++r) {
            unsigned b1 = 0, b2 = 0;
            #pragma unroll
            for (int n = 0; n < 4; ++n) {
                float s = acc[m][n][r];
                int cib = (wn << 6) + (n << 4) + lr;     // col-in-block
                unsigned u = __float_as_uint(s);
                u = (u & 0x80000000u) ? ~u : (u | 0x80000000u);
                unsigned key = (u & 0xFFFFFF80u) | (unsigned)(127 - cib);
                if (key > b1) { b2 = b1; b1 = key; }
                else if (key > b2) b2 = key;
            }
            #pragma unroll
            for (int d = 1; d < 16; d <<= 1) {   // top-2 merge across 16 cols
                unsigned o1 = __shfl_xor(b1, d), o2 = __shfl_xor(b2, d);
                if (o1 > b1) { b2 = (b1 > o2) ? b1 : o2; b1 = o1; }
                else if (o1 > b2) b2 = o1;
            }
            k1[m][r] = b1; k2[m][r] = b2;
        }
    }
    __syncthreads();
    if (wn == 0 && lr == 0) {
        #pragma unroll
        for (int m = 0; m < 4; ++m)
            #pragma unroll
            for (int r = 0; r < 4; ++r) {
                int rl = (wm << 6) + (m << 4) + (g << 2) + r;
                lk[rl * 2] = k1[m][r];
                lk[rl * 2 + 1] = k2[m][r];
            }
    }
    __syncthreads();
    if (wn == 1 && lr == 0) {
        #pragma unroll
        for (int m = 0; m < 4; ++m)
            #pragma unroll
            for (int r = 0; r < 4; ++r) {
                int rl = (wm << 6) + (m << 4) + (g << 2) + r;
                unsigned b1 = k1[m][r], b2 = k2[m][r];
                unsigned o1 = lk[rl * 2], o2 = lk[rl * 2 + 1];
                if (o1 > b1) { b2 = (b1 > o2) ? b1 : o2; b1 = o1; }
                else if (o1 > b2) b2 = o1;
                uint2 out; out.x = b1; out.y = b2;
                *(uint2*)&pkeys[((size_t)(row0 + rl) << 6) + (cb << 1)] = out;
            }
    }
}

// ---------------------------------------------------------------------------
// Kernel 2: fused exact fp64 refine + gather + loss partial. One wave/token.
// 64 coalesced candidate keys; rescore all within 2e-3 of max in fp64
// (2 x.e - e.e), pick max (tie -> lowest index). Then write quantized =
// embed[best] (exact fp32 copy), per-token ||x-q||^2, index-as-float.
// ---------------------------------------------------------------------------
__global__ __launch_bounds__(64) void refine_gather_kernel(
    const float* __restrict__ X, const float* __restrict__ E,
    const unsigned* __restrict__ pkeys, float* __restrict__ outq,
    float* __restrict__ outidx, float* __restrict__ sums)
{
    int token = blockIdx.x;
    int lane = threadIdx.x;
    unsigned k = pkeys[((size_t)token << 6) + lane];
    unsigned m = k & 0xFFFFFF80u;
    float s = __uint_as_float((m & 0x80000000u) ? (m & 0x7FFFFFFFu) : ~m);
    float smax = s;
    #pragma unroll
    for (int d = 1; d < 64; d <<= 1) smax = fmaxf(smax, __shfl_xor(smax, d));
    bool cand = s >= smax - 2e-3f;
    unsigned long long ball = __ballot(cand);

    const float* x = X + (size_t)token * DIM;
    float xr[20];
    #pragma unroll
    for (int j = 0; j < 20; ++j) xr[j] = x[j * 64 + lane];

    double best_s = -1.0e300;
    int best_i = 0x7FFFFFFF;
    while (ball) {
        int src = __ffsll(ball) - 1;
        ball &= ball - 1;
        unsigned ck = __shfl(k, src);
        int cidx = ((src >> 1) << 7) + (127 - (int)(ck & 127u));
        const float* e = E + (size_t)cidx * DIM;
        double d = 0.0, ee = 0.0;
        #pragma unroll
        for (int j = 0; j < 20; ++j) {
            double ev = (double)e[j * 64 + lane];
            d += (double)xr[j] * ev;
            ee += ev * ev;
        }
        #pragma unroll
        for (int dd = 1; dd < 64; dd <<= 1) {
            d += __shfl_xor(d, dd);
            ee += __shfl_xor(ee, dd);
        }
        double sc = 2.0 * d - ee;
        if (sc > best_s || (sc == best_s && cidx < best_i)) { best_s = sc; best_i = cidx; }
    }

    // gather + commit-loss partial
    const float4* e4 = (const float4*)(E + (size_t)best_i * DIM);
    const float4* x4 = (const float4*)x;
    float4* o4 = (float4*)(outq + (size_t)token * DIM);
    float local = 0.0f;
    #pragma unroll
    for (int j = 0; j < 5; ++j) {
        float4 q = e4[j * 64 + lane];
        float4 xv = x4[j * 64 + lane];
        o4[j * 64 + lane] = q;
        float dx = xv.x - q.x, dy = xv.y - q.y, dz = xv.z - q.z, dw = xv.w - q.w;
        local += dx * dx + dy * dy + dz * dz + dw * dw;
    }
    #pragma unroll
    for (int d = 1; d < 64; d <<= 1) local += __shfl_xor(local, d);
    if (lane == 0) {
        sums[token] = local;
        outidx[token] = (float)best_i;
    }
}

// ---------------------------------------------------------------------------
// Kernel 3: deterministic final loss reduction (fixed tree).
// ---------------------------------------------------------------------------
__global__ __launch_bounds__(256) void loss_kernel(
    const float* __restrict__ sums, float* __restrict__ out_loss)
{
    __shared__ double red[256];
    int t = threadIdx.x;
    double s = 0.0;
    for (int i = t; i < N_TOKENS; i += 256) s += (double)sums[i];
    red[t] = s;
    __syncthreads();
    for (int off = 128; off > 0; off >>= 1) {
        if (t < off) red[t] += red[t + off];
        __syncthreads();
    }
    if (t == 0) out_loss[0] = (float)(red[0] / (double)((size_t)N_TOKENS * DIM));
}

extern "C" void kernel_launch(void* const* d_in, const int* in_sizes, int n_in,
                              void* d_out, int out_size, void* d_ws, size_t ws_size,
                              hipStream_t stream)
{
    const float* X = (const float*)d_in[0];   // (32768, 1280) fp32, L2-normalized
    const float* E = (const float*)d_in[1];   // (4096, 1280) fp32, L2-normalized

    float* outq = (float*)d_out;                       // (32768,1280)
    float* outidx = outq + (size_t)N_TOKENS * DIM;     // (32768,) as float
    float* outloss = outidx + N_TOKENS;                // scalar

    // workspace: pkeys 8 MB (top-2 u32 keys x 32 blocks, [token][64] coalesced)
    // | sums 128 KB. All rewritten every call.
    unsigned* pkeys = (unsigned*)d_ws;
    float* sums = (float*)((char*)d_ws + (size_t)N_TOKENS * 64 * sizeof(unsigned));

    gemm_argmax_kernel<<<dim3(8192), dim3(256), 0, stream>>>(X, E, pkeys);
    refine_gather_kernel<<<dim3(N_TOKENS), dim3(64), 0, stream>>>(X, E, pkeys, outq, outidx, sums);
    loss_kernel<<<dim3(1), dim3(256), 0, stream>>>(sums, outloss);
}

// Round 3
// 679.656 us; speedup vs baseline: 2.1636x; 1.3174x over previous
//
#include <hip/hip_runtime.h>
#include <hip/hip_bf16.h>

typedef __bf16 bf16x8 __attribute__((ext_vector_type(8)));
typedef float f32x4 __attribute__((ext_vector_type(4)));

#define N_TOKENS 32768
#define N_CODES 4096
#define DIM 1280
#define NCB 32  // column blocks = 4096/128
#define BK 64

__device__ __forceinline__ void load_lds16(const void* g, void* l) {
    __builtin_amdgcn_global_load_lds(
        (const __attribute__((address_space(1))) unsigned int*)g,
        (__attribute__((address_space(3))) unsigned int*)l,
        16, 0, 0);
}

// ---------------------------------------------------------------------------
// Kernel 0: fp32 -> bf16 (truncation) pre-convert, 8 elems/thread.
// Truncation numerics identical to round-2 (verified): random err sigma
// ~4.5e-5, systematic -0.4%*score uniform shrink (argmax-safe), covered by
// the fp64 refine threshold 2e-3.
// ---------------------------------------------------------------------------
__global__ __launch_bounds__(256) void convert_bf16_kernel(
    const float* __restrict__ src, unsigned short* __restrict__ dst, int n8)
{
    int i = blockIdx.x * 256 + threadIdx.x;
    if (i >= n8) return;
    const float4* s4 = (const float4*)src;
    float4 v0 = s4[(size_t)i * 2];
    float4 v1 = s4[(size_t)i * 2 + 1];
    uint4 p;
    p.x = (__float_as_uint(v0.y) & 0xFFFF0000u) | (__float_as_uint(v0.x) >> 16);
    p.y = (__float_as_uint(v0.w) & 0xFFFF0000u) | (__float_as_uint(v0.z) >> 16);
    p.z = (__float_as_uint(v1.y) & 0xFFFF0000u) | (__float_as_uint(v1.x) >> 16);
    p.w = (__float_as_uint(v1.w) & 0xFFFF0000u) | (__float_as_uint(v1.z) >> 16);
    ((uint4*)dst)[i] = p;
}

// ---------------------------------------------------------------------------
// Kernel 1: pure-bf16 GEMM (X[32768] x E[4096]^T over DIM=1280) with fused
// per-row TOP-2 argmax per 128-col block. m97 structure: global_load_lds
// width-16 staging (linear LDS dest), inverse-XOR-swizzled per-lane global
// source, XOR-swizzled ds_read_b128 (LDS[r][c] = G[r][c ^ (r&7)], 16B chunks
// of the 128B row) -> ~2-way bank aliasing (free).
// Key (u32) = monotone fp32 score, low 7 bits = (127 - col-in-block).
// ---------------------------------------------------------------------------
__global__ __launch_bounds__(256) void gemm_argmax_kernel(
    const unsigned short* __restrict__ Xb, const unsigned short* __restrict__ Eb,
    unsigned* __restrict__ pkeys)
{
    __shared__ unsigned short As[128 * BK];  // [row][k] bf16, 128B rows
    __shared__ unsigned short Bs[128 * BK];
    __shared__ unsigned lk[128 * 2];

    int bid = blockIdx.x;
    // bijective XCD swizzle: 8192 blocks over 8 XCDs
    int swz = (bid & 7) * 1024 + (bid >> 3);
    int rb = swz >> 5, cb = swz & 31;
    int row0 = rb << 7, col0 = cb << 7;

    int tid = threadIdx.x;
    int wid = tid >> 6, lane = tid & 63;
    int wm = wid >> 1, wn = wid & 1;
    int lr = lane & 15, g = lane >> 4;

    f32x4 acc[4][4] = {};

    for (int kt = 0; kt < DIM / BK; ++kt) {
        int k0 = kt * BK;
        __syncthreads();  // previous compute done before overwrite
        #pragma unroll
        for (int i = 0; i < 4; ++i) {
            int f = tid + (i << 8);              // 0..1023 lane-slots
            int r = f >> 3, c = f & 7;           // row, 16B-chunk in row
            int sc = c ^ (r & 7);                // inverse swizzle on source
            load_lds16(Xb + (size_t)(row0 + r) * DIM + k0 + (sc << 3), &As[f << 3]);
            load_lds16(Eb + (size_t)(col0 + r) * DIM + k0 + (sc << 3), &Bs[f << 3]);
        }
        __syncthreads();  // compiler drains vmcnt before s_barrier

        bf16x8 a[4][2], b[4][2];
        #pragma unroll
        for (int m = 0; m < 4; ++m) {
            int row = (wm << 6) + (m << 4) + lr;
            #pragma unroll
            for (int kk = 0; kk < 2; ++kk) {
                int c = (kk << 2) + g;
                a[m][kk] = *(const bf16x8*)&As[(row << 6) + ((c ^ (row & 7)) << 3)];
            }
        }
        #pragma unroll
        for (int n = 0; n < 4; ++n) {
            int row = (wn << 6) + (n << 4) + lr;
            #pragma unroll
            for (int kk = 0; kk < 2; ++kk) {
                int c = (kk << 2) + g;
                b[n][kk] = *(const bf16x8*)&Bs[(row << 6) + ((c ^ (row & 7)) << 3)];
            }
        }
        #pragma unroll
        for (int kk = 0; kk < 2; ++kk)
            #pragma unroll
            for (int m = 0; m < 4; ++m)
                #pragma unroll
                for (int n = 0; n < 4; ++n)
                    acc[m][n] = __builtin_amdgcn_mfma_f32_16x16x32_bf16(
                        a[m][kk], b[n][kk], acc[m][n], 0, 0, 0);
    }

    // epilogue (verified round 2): C/D col = lane&15, row = (lane>>4)*4 + reg
    unsigned k1[4][4], k2[4][4];
    #pragma unroll
    for (int m = 0; m < 4; ++m) {
        #pragma unroll
        for (int r = 0; r < 4; ++r) {
            unsigned b1 = 0, b2 = 0;
            #pragma unroll
            for (int n = 0; n < 4; ++n) {
                float s = acc[m][n][r];
                int cib = (wn << 6) + (n << 4) + lr;     // col-in-block
                unsigned u = __float_as_uint(s);
                u = (u & 0x80000000u) ? ~u : (u | 0x80000000u);
                unsigned key = (u & 0xFFFFFF80u) | (unsigned)(127 - cib);
                if (key > b1) { b2 = b1; b1 = key; }
                else if (key > b2) b2 = key;
            }
            #pragma unroll
            for (int d = 1; d < 16; d <<= 1) {   // top-2 merge across 16 cols
                unsigned o1 = __shfl_xor(b1, d), o2 = __shfl_xor(b2, d);
                if (o1 > b1) { b2 = (b1 > o2) ? b1 : o2; b1 = o1; }
                else if (o1 > b2) b2 = o1;
            }
            k1[m][r] = b1; k2[m][r] = b2;
        }
    }
    __syncthreads();
    if (wn == 0 && lr == 0) {
        #pragma unroll
        for (int m = 0; m < 4; ++m)
            #pragma unroll
            for (int r = 0; r < 4; ++r) {
                int rl = (wm << 6) + (m << 4) + (g << 2) + r;
                lk[rl * 2] = k1[m][r];
                lk[rl * 2 + 1] = k2[m][r];
            }
    }
    __syncthreads();
    if (wn == 1 && lr == 0) {
        #pragma unroll
        for (int m = 0; m < 4; ++m)
            #pragma unroll
            for (int r = 0; r < 4; ++r) {
                int rl = (wm << 6) + (m << 4) + (g << 2) + r;
                unsigned b1 = k1[m][r], b2 = k2[m][r];
                unsigned o1 = lk[rl * 2], o2 = lk[rl * 2 + 1];
                if (o1 > b1) { b2 = (b1 > o2) ? b1 : o2; b1 = o1; }
                else if (o1 > b2) b2 = o1;
                uint2 out; out.x = b1; out.y = b2;
                *(uint2*)&pkeys[((size_t)(row0 + rl) << 6) + (cb << 1)] = out;
            }
    }
}

// ---------------------------------------------------------------------------
// Kernel 2: fused exact fp64 refine + gather + loss partial. One wave/token.
// ---------------------------------------------------------------------------
__global__ __launch_bounds__(64) void refine_gather_kernel(
    const float* __restrict__ X, const float* __restrict__ E,
    const unsigned* __restrict__ pkeys, float* __restrict__ outq,
    float* __restrict__ outidx, float* __restrict__ sums)
{
    int token = blockIdx.x;
    int lane = threadIdx.x;
    unsigned k = pkeys[((size_t)token << 6) + lane];
    unsigned m = k & 0xFFFFFF80u;
    float s = __uint_as_float((m & 0x80000000u) ? (m & 0x7FFFFFFFu) : ~m);
    float smax = s;
    #pragma unroll
    for (int d = 1; d < 64; d <<= 1) smax = fmaxf(smax, __shfl_xor(smax, d));
    bool cand = s >= smax - 2e-3f;
    unsigned long long ball = __ballot(cand);

    const float* x = X + (size_t)token * DIM;
    float xr[20];
    #pragma unroll
    for (int j = 0; j < 20; ++j) xr[j] = x[j * 64 + lane];

    double best_s = -1.0e300;
    int best_i = 0x7FFFFFFF;
    while (ball) {
        int src = __ffsll(ball) - 1;
        ball &= ball - 1;
        unsigned ck = __shfl(k, src);
        int cidx = ((src >> 1) << 7) + (127 - (int)(ck & 127u));
        const float* e = E + (size_t)cidx * DIM;
        double d = 0.0, ee = 0.0;
        #pragma unroll
        for (int j = 0; j < 20; ++j) {
            double ev = (double)e[j * 64 + lane];
            d += (double)xr[j] * ev;
            ee += ev * ev;
        }
        #pragma unroll
        for (int dd = 1; dd < 64; dd <<= 1) {
            d += __shfl_xor(d, dd);
            ee += __shfl_xor(ee, dd);
        }
        double sc = 2.0 * d - ee;
        if (sc > best_s || (sc == best_s && cidx < best_i)) { best_s = sc; best_i = cidx; }
    }

    // gather + commit-loss partial
    const float4* e4 = (const float4*)(E + (size_t)best_i * DIM);
    const float4* x4 = (const float4*)x;
    float4* o4 = (float4*)(outq + (size_t)token * DIM);
    float local = 0.0f;
    #pragma unroll
    for (int j = 0; j < 5; ++j) {
        float4 q = e4[j * 64 + lane];
        float4 xv = x4[j * 64 + lane];
        o4[j * 64 + lane] = q;
        float dx = xv.x - q.x, dy = xv.y - q.y, dz = xv.z - q.z, dw = xv.w - q.w;
        local += dx * dx + dy * dy + dz * dz + dw * dw;
    }
    #pragma unroll
    for (int d = 1; d < 64; d <<= 1) local += __shfl_xor(local, d);
    if (lane == 0) {
        sums[token] = local;
        outidx[token] = (float)best_i;
    }
}

// ---------------------------------------------------------------------------
// Kernel 3: deterministic final loss reduction (fixed tree).
// ---------------------------------------------------------------------------
__global__ __launch_bounds__(256) void loss_kernel(
    const float* __restrict__ sums, float* __restrict__ out_loss)
{
    __shared__ double red[256];
    int t = threadIdx.x;
    double s = 0.0;
    for (int i = t; i < N_TOKENS; i += 256) s += (double)sums[i];
    red[t] = s;
    __syncthreads();
    for (int off = 128; off > 0; off >>= 1) {
        if (t < off) red[t] += red[t + off];
        __syncthreads();
    }
    if (t == 0) out_loss[0] = (float)(red[0] / (double)((size_t)N_TOKENS * DIM));
}

extern "C" void kernel_launch(void* const* d_in, const int* in_sizes, int n_in,
                              void* d_out, int out_size, void* d_ws, size_t ws_size,
                              hipStream_t stream)
{
    const float* X = (const float*)d_in[0];   // (32768, 1280) fp32, L2-normalized
    const float* E = (const float*)d_in[1];   // (4096, 1280) fp32, L2-normalized

    float* outq = (float*)d_out;                       // (32768,1280)
    float* outidx = outq + (size_t)N_TOKENS * DIM;     // (32768,) as float
    float* outloss = outidx + N_TOKENS;                // scalar

    // bf16 temps live INSIDE the outq region (94.4 MB used of 167.8 MB);
    // refine_gather_kernel later overwrites the whole region with the real
    // output, in-stream after the GEMM has consumed the temps.
    unsigned short* Xbf = (unsigned short*)d_out;                 // 83.9 MB
    unsigned short* Ebf = Xbf + (size_t)N_TOKENS * DIM;           // 10.5 MB

    // workspace: pkeys 8 MB (top-2 u32 keys x 32 blocks, [token][64]) | sums
    unsigned* pkeys = (unsigned*)d_ws;
    float* sums = (float*)((char*)d_ws + (size_t)N_TOKENS * 64 * sizeof(unsigned));

    convert_bf16_kernel<<<dim3((N_TOKENS * (DIM / 8) + 255) / 256), dim3(256), 0, stream>>>(
        X, Xbf, N_TOKENS * (DIM / 8));
    convert_bf16_kernel<<<dim3((N_CODES * (DIM / 8) + 255) / 256), dim3(256), 0, stream>>>(
        E, Ebf, N_CODES * (DIM / 8));
    gemm_argmax_kernel<<<dim3(8192), dim3(256), 0, stream>>>(Xbf, Ebf, pkeys);
    refine_gather_kernel<<<dim3(N_TOKENS), dim3(64), 0, stream>>>(X, E, pkeys, outq, outidx, sums);
    loss_kernel<<<dim3(1), dim3(256), 0, stream>>>(sums, outloss);
}

// Round 4
// 547.810 us; speedup vs baseline: 2.6843x; 1.2407x over previous
//
#include <hip/hip_runtime.h>
#include <hip/hip_bf16.h>

typedef __bf16 bf16x8 __attribute__((ext_vector_type(8)));
typedef float f32x4 __attribute__((ext_vector_type(4)));

#define N_TOKENS 32768
#define N_CODES 4096
#define DIM 1280
#define NT 40            // K-tiles of 32
#define BUFSZ 32768      // A 16KB + B 16KB per K-tile buffer

__device__ __forceinline__ void load_lds16(const void* g, void* l) {
    __builtin_amdgcn_global_load_lds(
        (const __attribute__((address_space(1))) unsigned int*)g,
        (__attribute__((address_space(3))) unsigned int*)l,
        16, 0, 0);
}

// ---------------------------------------------------------------------------
// Kernel 0: fp32 -> bf16 (truncation) pre-convert. Verified numerics (r2/r3).
// ---------------------------------------------------------------------------
__global__ __launch_bounds__(256) void convert_bf16_kernel(
    const float* __restrict__ src, unsigned short* __restrict__ dst, int n8)
{
    int i = blockIdx.x * 256 + threadIdx.x;
    if (i >= n8) return;
    const float4* s4 = (const float4*)src;
    float4 v0 = s4[(size_t)i * 2];
    float4 v1 = s4[(size_t)i * 2 + 1];
    uint4 p;
    p.x = (__float_as_uint(v0.y) & 0xFFFF0000u) | (__float_as_uint(v0.x) >> 16);
    p.y = (__float_as_uint(v0.w) & 0xFFFF0000u) | (__float_as_uint(v0.z) >> 16);
    p.z = (__float_as_uint(v1.y) & 0xFFFF0000u) | (__float_as_uint(v1.x) >> 16);
    p.w = (__float_as_uint(v1.w) & 0xFFFF0000u) | (__float_as_uint(v1.z) >> 16);
    ((uint4*)dst)[i] = p;
}

// ---------------------------------------------------------------------------
// Kernel 1: bf16 GEMM 256x256 tile, 8 waves (2 wm x 4 wn), BK=32, 4 LDS
// buffers, prefetch depth 3, counted vmcnt(8) + raw s_barrier (no drain).
// Fused per-row TOP-2 argmax per 128-col block (2 blocks per tile).
// LDS layout: paired rows (2 token rows per 128B LDS row), 16B chunk c of
// pair rp stored at c ^ (rp&7); global source pre-swizzled (both-sides rule).
// Ledger: end of iter t -> outstanding STAGE(t+1,t+2,t+3)=12 loads; vmcnt(8)
// completes tile t+1 (own wave), barrier joins all waves => tile t+1 LDS
// globally complete. STAGE(t+3) at iter t writes buf[(t+3)&3], last read at
// iter t-1 before its end-barrier => no overwrite race.
// ---------------------------------------------------------------------------
__global__ __launch_bounds__(512, 2) void gemm_argmax_kernel(
    const unsigned short* __restrict__ Xb, const unsigned short* __restrict__ Eb,
    unsigned* __restrict__ pkeys)
{
    __shared__ __align__(16) char lds[4 * BUFSZ];   // 128 KB

    int bid = blockIdx.x;
    // bijective XCD swizzle, cb0-major within XCD (B-panel stays in L2)
    int swz = (bid & 7) * 256 + (bid >> 3);
    int cb0 = swz >> 7, rb = swz & 127;
    int row0 = rb << 8, col0 = cb0 << 8;

    int tid = threadIdx.x;
    int wid = tid >> 6, lane = tid & 63;
    int wm = wid >> 2, wn = wid & 3;
    int lr = lane & 15, g = lane >> 4;

    // per-lane constant swizzled fragment offsets
    int slot = (((lr & 1) << 2) + g) ^ ((lr >> 1) & 7);
    int aoff = ((wm << 6) + (lr >> 1)) * 128 + slot * 16;            // A region
    int boff = 16384 + ((wn << 5) + (lr >> 1)) * 128 + slot * 16;    // B region

    f32x4 acc[8][4] = {};

    auto STAGE = [&](int t) {
        int base = (t & 3) * BUFSZ;
        int k0 = t << 5;
        #pragma unroll
        for (int i = 0; i < 2; ++i) {
            int f = tid + (i << 9);          // slot 0..1023
            int rp = f >> 3, c = f & 7;
            int cp = c ^ (rp & 7);           // pre-swizzled source chunk
            int gr = (rp << 1) + (cp >> 2);  // global row in tile
            int kc = k0 + ((cp & 3) << 3);
            load_lds16(Xb + (size_t)(row0 + gr) * DIM + kc, lds + base + (f << 4));
            load_lds16(Eb + (size_t)(col0 + gr) * DIM + kc, lds + base + 16384 + (f << 4));
        }
    };

    auto COMPUTE = [&](int t) {
        int base = (t & 3) * BUFSZ;
        const char* pA = lds + base + aoff;
        const char* pB = lds + base + boff;
        bf16x8 a[8], b[4];
        #pragma unroll
        for (int m = 0; m < 8; ++m) a[m] = *(const bf16x8*)(pA + (m << 10));
        #pragma unroll
        for (int n = 0; n < 4; ++n) b[n] = *(const bf16x8*)(pB + (n << 10));
        __builtin_amdgcn_s_setprio(1);
        #pragma unroll
        for (int m = 0; m < 8; ++m)
            #pragma unroll
            for (int n = 0; n < 4; ++n)
                acc[m][n] = __builtin_amdgcn_mfma_f32_16x16x32_bf16(
                    a[m], b[n], acc[m][n], 0, 0, 0);
        __builtin_amdgcn_s_setprio(0);
    };

    // prologue: stage tiles 0,1,2; wait tile 0 (oldest 4 of 12); join
    STAGE(0); STAGE(1); STAGE(2);
    asm volatile("s_waitcnt vmcnt(8)" ::: "memory");
    __builtin_amdgcn_s_barrier();
    __builtin_amdgcn_sched_barrier(0);

    for (int t = 0; t < NT - 3; ++t) {
        STAGE(t + 3);
        COMPUTE(t);
        asm volatile("s_waitcnt vmcnt(8)" ::: "memory");
        __builtin_amdgcn_s_barrier();
        __builtin_amdgcn_sched_barrier(0);
    }
    COMPUTE(NT - 3);
    asm volatile("s_waitcnt vmcnt(4)" ::: "memory");
    __builtin_amdgcn_s_barrier();
    __builtin_amdgcn_sched_barrier(0);
    COMPUTE(NT - 2);
    asm volatile("s_waitcnt vmcnt(0)" ::: "memory");
    __builtin_amdgcn_s_barrier();
    __builtin_amdgcn_sched_barrier(0);
    COMPUTE(NT - 1);
    __syncthreads();   // full drain; LDS reused for epilogue merge

    // ---- fused top-2 argmax epilogue ----
    // C/D frag layout: col = lr, row = g*4 + r. Wave covers rows
    // wm*128 + m*16 + g*4 + r, cols wn*64 + n*16 + lr.
    uint2* lk2 = (uint2*)lds;   // [256 rows][4 wn]
    #pragma unroll
    for (int m = 0; m < 8; ++m) {
        #pragma unroll
        for (int r = 0; r < 4; ++r) {
            unsigned b1 = 0, b2 = 0;
            #pragma unroll
            for (int n = 0; n < 4; ++n) {
                float s = acc[m][n][r];
                int cib = ((wn & 1) << 6) + (n << 4) + lr;   // col in 128-block
                unsigned u = __float_as_uint(s);
                u = (u & 0x80000000u) ? ~u : (u | 0x80000000u);
                unsigned key = (u & 0xFFFFFF80u) | (unsigned)(127 - cib);
                if (key > b1) { b2 = b1; b1 = key; }
                else if (key > b2) b2 = key;
            }
            #pragma unroll
            for (int d = 1; d < 16; d <<= 1) {   // merge across 16 lanes (lr)
                unsigned o1 = __shfl_xor(b1, d), o2 = __shfl_xor(b2, d);
                if (o1 > b1) { b2 = (b1 > o2) ? b1 : o2; b1 = o1; }
                else if (o1 > b2) b2 = o1;
            }
            if (lr == 0) {
                int row = (wm << 7) + (m << 4) + (g << 2) + r;
                uint2 v; v.x = b1; v.y = b2;
                lk2[(row << 2) + wn] = v;
            }
        }
    }
    __syncthreads();
    {
        // 512 threads: one (row, col-128-block-half) each
        int row = tid >> 1, h = tid & 1;
        uint2 p0 = lk2[(row << 2) + (h << 1)];
        uint2 p1 = lk2[(row << 2) + (h << 1) + 1];
        unsigned b1 = p0.x, b2 = p0.y;
        if (p1.x > b1) { b2 = (b1 > p1.y) ? b1 : p1.y; b1 = p1.x; }
        else if (p1.x > b2) b2 = p1.x;
        uint2 out; out.x = b1; out.y = b2;
        *(uint2*)&pkeys[((size_t)(row0 + row) << 6) + (((cb0 << 1) + h) << 1)] = out;
    }
}

// ---------------------------------------------------------------------------
// Kernel 2: fused exact fp64 refine + gather + loss partial. One wave/token.
// ---------------------------------------------------------------------------
__global__ __launch_bounds__(64) void refine_gather_kernel(
    const float* __restrict__ X, const float* __restrict__ E,
    const unsigned* __restrict__ pkeys, float* __restrict__ outq,
    float* __restrict__ outidx, float* __restrict__ sums)
{
    int token = blockIdx.x;
    int lane = threadIdx.x;
    unsigned k = pkeys[((size_t)token << 6) + lane];
    unsigned m = k & 0xFFFFFF80u;
    float s = __uint_as_float((m & 0x80000000u) ? (m & 0x7FFFFFFFu) : ~m);
    float smax = s;
    #pragma unroll
    for (int d = 1; d < 64; d <<= 1) smax = fmaxf(smax, __shfl_xor(smax, d));
    bool cand = s >= smax - 2e-3f;
    unsigned long long ball = __ballot(cand);

    const float* x = X + (size_t)token * DIM;
    float xr[20];
    #pragma unroll
    for (int j = 0; j < 20; ++j) xr[j] = x[j * 64 + lane];

    double best_s = -1.0e300;
    int best_i = 0x7FFFFFFF;
    while (ball) {
        int src = __ffsll(ball) - 1;
        ball &= ball - 1;
        unsigned ck = __shfl(k, src);
        int cidx = ((src >> 1) << 7) + (127 - (int)(ck & 127u));
        const float* e = E + (size_t)cidx * DIM;
        double d = 0.0, ee = 0.0;
        #pragma unroll
        for (int j = 0; j < 20; ++j) {
            double ev = (double)e[j * 64 + lane];
            d += (double)xr[j] * ev;
            ee += ev * ev;
        }
        #pragma unroll
        for (int dd = 1; dd < 64; dd <<= 1) {
            d += __shfl_xor(d, dd);
            ee += __shfl_xor(ee, dd);
        }
        double sc = 2.0 * d - ee;
        if (sc > best_s || (sc == best_s && cidx < best_i)) { best_s = sc; best_i = cidx; }
    }

    // gather + commit-loss partial
    const float4* e4 = (const float4*)(E + (size_t)best_i * DIM);
    const float4* x4 = (const float4*)x;
    float4* o4 = (float4*)(outq + (size_t)token * DIM);
    float local = 0.0f;
    #pragma unroll
    for (int j = 0; j < 5; ++j) {
        float4 q = e4[j * 64 + lane];
        float4 xv = x4[j * 64 + lane];
        o4[j * 64 + lane] = q;
        float dx = xv.x - q.x, dy = xv.y - q.y, dz = xv.z - q.z, dw = xv.w - q.w;
        local += dx * dx + dy * dy + dz * dz + dw * dw;
    }
    #pragma unroll
    for (int d = 1; d < 64; d <<= 1) local += __shfl_xor(local, d);
    if (lane == 0) {
        sums[token] = local;
        outidx[token] = (float)best_i;
    }
}

// ---------------------------------------------------------------------------
// Kernel 3: deterministic final loss reduction (fixed tree).
// ---------------------------------------------------------------------------
__global__ __launch_bounds__(256) void loss_kernel(
    const float* __restrict__ sums, float* __restrict__ out_loss)
{
    __shared__ double red[256];
    int t = threadIdx.x;
    double s = 0.0;
    for (int i = t; i < N_TOKENS; i += 256) s += (double)sums[i];
    red[t] = s;
    __syncthreads();
    for (int off = 128; off > 0; off >>= 1) {
        if (t < off) red[t] += red[t + off];
        __syncthreads();
    }
    if (t == 0) out_loss[0] = (float)(red[0] / (double)((size_t)N_TOKENS * DIM));
}

extern "C" void kernel_launch(void* const* d_in, const int* in_sizes, int n_in,
                              void* d_out, int out_size, void* d_ws, size_t ws_size,
                              hipStream_t stream)
{
    const float* X = (const float*)d_in[0];   // (32768, 1280) fp32
    const float* E = (const float*)d_in[1];   // (4096, 1280) fp32

    float* outq = (float*)d_out;                       // (32768,1280)
    float* outidx = outq + (size_t)N_TOKENS * DIM;     // (32768,) as float
    float* outloss = outidx + N_TOKENS;                // scalar

    // bf16 temps inside outq region (94.4 MB of 167.8 MB); consumed by GEMM,
    // then fully overwritten by refine_gather in-stream.
    unsigned short* Xbf = (unsigned short*)d_out;               // 83.9 MB
    unsigned short* Ebf = Xbf + (size_t)N_TOKENS * DIM;         // 10.5 MB

    unsigned* pkeys = (unsigned*)d_ws;                          // 8 MB
    float* sums = (float*)((char*)d_ws + (size_t)N_TOKENS * 64 * sizeof(unsigned));

    convert_bf16_kernel<<<dim3((N_TOKENS * (DIM / 8) + 255) / 256), dim3(256), 0, stream>>>(
        X, Xbf, N_TOKENS * (DIM / 8));
    convert_bf16_kernel<<<dim3((N_CODES * (DIM / 8) + 255) / 256), dim3(256), 0, stream>>>(
        E, Ebf, N_CODES * (DIM / 8));
    gemm_argmax_kernel<<<dim3(2048), dim3(512), 0, stream>>>(Xbf, Ebf, pkeys);
    refine_gather_kernel<<<dim3(N_TOKENS), dim3(64), 0, stream>>>(X, E, pkeys, outq, outidx, sums);
    loss_kernel<<<dim3(1), dim3(256), 0, stream>>>(sums, outloss);
}

// Round 5
// 437.857 us; speedup vs baseline: 3.3584x; 1.2511x over previous
//
#include <hip/hip_runtime.h>
#include <hip/hip_bf16.h>

typedef int i32x4 __attribute__((ext_vector_type(4)));

#define N_TOKENS 32768
#define N_CODES 4096
#define DIM 1280
#define NT 20            // K-tiles of 64 (i8)
#define BUFSZ 32768      // A 16KB + B 16KB per K-tile buffer

__device__ __forceinline__ void load_lds16(const void* g, void* l) {
    __builtin_amdgcn_global_load_lds(
        (const __attribute__((address_space(1))) unsigned int*)g,
        (__attribute__((address_space(3))) unsigned int*)l,
        16, 0, 0);
}

// ---------------------------------------------------------------------------
// Kernel 0: per-row symmetric int8 quantize (RNE). q = rint(x*127/rowmax),
// scale[row] = rowmax/127. One wave per row. Since rows are L2-normalized,
// rowmax >= 1/sqrt(DIM); guard anyway. Exact-int dot => score err sigma
// ~3.4e-4, zero-mean; refine threshold 3e-3 ~ 9 sigma.
// ---------------------------------------------------------------------------
__global__ __launch_bounds__(256) void quantize_i8_kernel(
    const float* __restrict__ src, signed char* __restrict__ dst,
    float* __restrict__ scale, int nrows)
{
    int row = blockIdx.x * 4 + (threadIdx.x >> 6);
    if (row >= nrows) return;
    int lane = threadIdx.x & 63;
    const float4* s4 = (const float4*)(src + (size_t)row * DIM);
    float4 v[5];
    float amax = 0.f;
    #pragma unroll
    for (int j = 0; j < 5; ++j) {
        v[j] = s4[j * 64 + lane];
        amax = fmaxf(amax, fmaxf(fmaxf(fabsf(v[j].x), fabsf(v[j].y)),
                                 fmaxf(fabsf(v[j].z), fabsf(v[j].w))));
    }
    #pragma unroll
    for (int d = 1; d < 64; d <<= 1) amax = fmaxf(amax, __shfl_xor(amax, d));
    amax = fmaxf(amax, 1e-20f);
    float inv = 127.0f / amax;
    int* d4 = (int*)(dst + (size_t)row * DIM);
    #pragma unroll
    for (int j = 0; j < 5; ++j) {
        int q0 = (int)rintf(v[j].x * inv), q1 = (int)rintf(v[j].y * inv);
        int q2 = (int)rintf(v[j].z * inv), q3 = (int)rintf(v[j].w * inv);
        d4[j * 64 + lane] = (q0 & 0xFF) | ((q1 & 0xFF) << 8) |
                            ((q2 & 0xFF) << 16) | ((q3 & 0xFF) << 24);
    }
    if (lane == 0) scale[row] = amax * (1.0f / 127.0f);
}

// ---------------------------------------------------------------------------
// Kernel 1: i8 GEMM 256x256 tile, 8 waves, BK=64, mfma_i32_16x16x64_i8.
// Schedule IDENTICAL to verified round-4 ledger (4 LDS buffers, depth-3
// prefetch, counted vmcnt(8), raw s_barrier): BK=64 i8 is byte-identical
// LDS geometry to BK=32 bf16 (64B rows paired into 128B LDS rows, 8x16B
// chunks, chunk c of pair rp stored at c^(rp&7), source pre-swizzled).
// Epilogue dequant: s = (float)int_dot * sx[row]*se[col]; then verified
// monotone-key TOP-2 per 128-col block.
// Ledger: end of iter t -> outstanding STAGE(t+1,t+2,t+3)=12 loads/wave;
// vmcnt(8) completes tile t+1, barrier joins all waves; STAGE(t+3) writes
// buf[(t+3)&3], last read iter t-1 pre-barrier => no overwrite race.
// ---------------------------------------------------------------------------
__global__ __launch_bounds__(512, 2) void gemm_argmax_kernel(
    const signed char* __restrict__ Xq, const signed char* __restrict__ Eq,
    const float* __restrict__ sx, const float* __restrict__ se,
    unsigned* __restrict__ pkeys)
{
    __shared__ __align__(16) char lds[4 * BUFSZ];   // 128 KB

    int bid = blockIdx.x;
    // bijective XCD swizzle, cb0-major within XCD (B-panel stays in L2)
    int swz = (bid & 7) * 256 + (bid >> 3);
    int cb0 = swz >> 7, rb = swz & 127;
    int row0 = rb << 8, col0 = cb0 << 8;

    int tid = threadIdx.x;
    int wid = tid >> 6, lane = tid & 63;
    int wm = wid >> 2, wn = wid & 3;
    int lr = lane & 15, g = lane >> 4;

    // per-lane constant swizzled fragment offsets (same geometry as r4)
    int slot = (((lr & 1) << 2) + g) ^ ((lr >> 1) & 7);
    int aoff = ((wm << 6) + (lr >> 1)) * 128 + slot * 16;            // A region
    int boff = 16384 + ((wn << 5) + (lr >> 1)) * 128 + slot * 16;    // B region

    i32x4 acc[8][4] = {};

    auto STAGE = [&](int t) {
        int base = (t & 3) * BUFSZ;
        int k0 = t << 6;                     // byte offset in row (i8)
        #pragma unroll
        for (int i = 0; i < 2; ++i) {
            int f = tid + (i << 9);          // slot 0..1023
            int rp = f >> 3, c = f & 7;
            int cp = c ^ (rp & 7);           // pre-swizzled source chunk
            int gr = (rp << 1) + (cp >> 2);  // global row in tile
            int kc = k0 + ((cp & 3) << 4);   // 16B k-chunk
            load_lds16(Xq + (size_t)(row0 + gr) * DIM + kc, lds + base + (f << 4));
            load_lds16(Eq + (size_t)(col0 + gr) * DIM + kc, lds + base + 16384 + (f << 4));
        }
    };

    auto COMPUTE = [&](int t) {
        int base = (t & 3) * BUFSZ;
        const char* pA = lds + base + aoff;
        const char* pB = lds + base + boff;
        i32x4 a[8], b[4];
        #pragma unroll
        for (int m = 0; m < 8; ++m) a[m] = *(const i32x4*)(pA + (m << 10));
        #pragma unroll
        for (int n = 0; n < 4; ++n) b[n] = *(const i32x4*)(pB + (n << 10));
        __builtin_amdgcn_s_setprio(1);
        #pragma unroll
        for (int m = 0; m < 8; ++m)
            #pragma unroll
            for (int n = 0; n < 4; ++n)
                acc[m][n] = __builtin_amdgcn_mfma_i32_16x16x64_i8(
                    a[m], b[n], acc[m][n], 0, 0, 0);
        __builtin_amdgcn_s_setprio(0);
    };

    STAGE(0); STAGE(1); STAGE(2);
    asm volatile("s_waitcnt vmcnt(8)" ::: "memory");
    __builtin_amdgcn_s_barrier();
    __builtin_amdgcn_sched_barrier(0);

    for (int t = 0; t < NT - 3; ++t) {
        STAGE(t + 3);
        COMPUTE(t);
        asm volatile("s_waitcnt vmcnt(8)" ::: "memory");
        __builtin_amdgcn_s_barrier();
        __builtin_amdgcn_sched_barrier(0);
    }
    COMPUTE(NT - 3);
    asm volatile("s_waitcnt vmcnt(4)" ::: "memory");
    __builtin_amdgcn_s_barrier();
    __builtin_amdgcn_sched_barrier(0);
    COMPUTE(NT - 2);
    asm volatile("s_waitcnt vmcnt(0)" ::: "memory");
    __builtin_amdgcn_s_barrier();
    __builtin_amdgcn_sched_barrier(0);
    COMPUTE(NT - 1);
    __syncthreads();   // full drain; LDS reused for epilogue merge

    // ---- dequant + fused top-2 argmax epilogue ----
    // C/D frag layout (dtype-independent): col = lr, row = g*4 + r.
    float se_l[4];
    #pragma unroll
    for (int n = 0; n < 4; ++n)
        se_l[n] = se[col0 + (wn << 6) + (n << 4) + lr];

    uint2* lk2 = (uint2*)lds;   // [256 rows][4 wn]
    #pragma unroll
    for (int m = 0; m < 8; ++m) {
        #pragma unroll
        for (int r = 0; r < 4; ++r) {
            int row = (wm << 7) + (m << 4) + (g << 2) + r;
            float fx = sx[row0 + row];
            unsigned b1 = 0, b2 = 0;
            #pragma unroll
            for (int n = 0; n < 4; ++n) {
                float s = (float)acc[m][n][r] * (fx * se_l[n]);
                int cib = ((wn & 1) << 6) + (n << 4) + lr;   // col in 128-block
                unsigned u = __float_as_uint(s);
                u = (u & 0x80000000u) ? ~u : (u | 0x80000000u);
                unsigned key = (u & 0xFFFFFF80u) | (unsigned)(127 - cib);
                if (key > b1) { b2 = b1; b1 = key; }
                else if (key > b2) b2 = key;
            }
            #pragma unroll
            for (int d = 1; d < 16; d <<= 1) {   // merge across 16 lanes (lr)
                unsigned o1 = __shfl_xor(b1, d), o2 = __shfl_xor(b2, d);
                if (o1 > b1) { b2 = (b1 > o2) ? b1 : o2; b1 = o1; }
                else if (o1 > b2) b2 = o1;
            }
            if (lr == 0) {
                uint2 v; v.x = b1; v.y = b2;
                lk2[(row << 2) + wn] = v;
            }
        }
    }
    __syncthreads();
    {
        int row = tid >> 1, h = tid & 1;
        uint2 p0 = lk2[(row << 2) + (h << 1)];
        uint2 p1 = lk2[(row << 2) + (h << 1) + 1];
        unsigned b1 = p0.x, b2 = p0.y;
        if (p1.x > b1) { b2 = (b1 > p1.y) ? b1 : p1.y; b1 = p1.x; }
        else if (p1.x > b2) b2 = p1.x;
        uint2 out; out.x = b1; out.y = b2;
        *(uint2*)&pkeys[((size_t)(row0 + row) << 6) + (((cb0 << 1) + h) << 1)] = out;
    }
}

// ---------------------------------------------------------------------------
// Kernel 2: fused exact fp64 refine + gather + loss partial. One wave/token.
// Threshold 3e-3 (~9 sigma of i8 quant noise).
// ---------------------------------------------------------------------------
__global__ __launch_bounds__(64) void refine_gather_kernel(
    const float* __restrict__ X, const float* __restrict__ E,
    const unsigned* __restrict__ pkeys, float* __restrict__ outq,
    float* __restrict__ outidx, float* __restrict__ sums)
{
    int token = blockIdx.x;
    int lane = threadIdx.x;
    unsigned k = pkeys[((size_t)token << 6) + lane];
    unsigned m = k & 0xFFFFFF80u;
    float s = __uint_as_float((m & 0x80000000u) ? (m & 0x7FFFFFFFu) : ~m);
    float smax = s;
    #pragma unroll
    for (int d = 1; d < 64; d <<= 1) smax = fmaxf(smax, __shfl_xor(smax, d));
    bool cand = s >= smax - 3e-3f;
    unsigned long long ball = __ballot(cand);

    const float* x = X + (size_t)token * DIM;
    float xr[20];
    #pragma unroll
    for (int j = 0; j < 20; ++j) xr[j] = x[j * 64 + lane];

    double best_s = -1.0e300;
    int best_i = 0x7FFFFFFF;
    while (ball) {
        int src = __ffsll(ball) - 1;
        ball &= ball - 1;
        unsigned ck = __shfl(k, src);
        int cidx = ((src >> 1) << 7) + (127 - (int)(ck & 127u));
        const float* e = E + (size_t)cidx * DIM;
        double d = 0.0, ee = 0.0;
        #pragma unroll
        for (int j = 0; j < 20; ++j) {
            double ev = (double)e[j * 64 + lane];
            d += (double)xr[j] * ev;
            ee += ev * ev;
        }
        #pragma unroll
        for (int dd = 1; dd < 64; dd <<= 1) {
            d += __shfl_xor(d, dd);
            ee += __shfl_xor(ee, dd);
        }
        double sc = 2.0 * d - ee;
        if (sc > best_s || (sc == best_s && cidx < best_i)) { best_s = sc; best_i = cidx; }
    }

    // gather + commit-loss partial
    const float4* e4 = (const float4*)(E + (size_t)best_i * DIM);
    const float4* x4 = (const float4*)x;
    float4* o4 = (float4*)(outq + (size_t)token * DIM);
    float local = 0.0f;
    #pragma unroll
    for (int j = 0; j < 5; ++j) {
        float4 q = e4[j * 64 + lane];
        float4 xv = x4[j * 64 + lane];
        o4[j * 64 + lane] = q;
        float dx = xv.x - q.x, dy = xv.y - q.y, dz = xv.z - q.z, dw = xv.w - q.w;
        local += dx * dx + dy * dy + dz * dz + dw * dw;
    }
    #pragma unroll
    for (int d = 1; d < 64; d <<= 1) local += __shfl_xor(local, d);
    if (lane == 0) {
        sums[token] = local;
        outidx[token] = (float)best_i;
    }
}

// ---------------------------------------------------------------------------
// Kernel 3: deterministic final loss reduction (fixed tree).
// ---------------------------------------------------------------------------
__global__ __launch_bounds__(256) void loss_kernel(
    const float* __restrict__ sums, float* __restrict__ out_loss)
{
    __shared__ double red[256];
    int t = threadIdx.x;
    double s = 0.0;
    for (int i = t; i < N_TOKENS; i += 256) s += (double)sums[i];
    red[t] = s;
    __syncthreads();
    for (int off = 128; off > 0; off >>= 1) {
        if (t < off) red[t] += red[t + off];
        __syncthreads();
    }
    if (t == 0) out_loss[0] = (float)(red[0] / (double)((size_t)N_TOKENS * DIM));
}

extern "C" void kernel_launch(void* const* d_in, const int* in_sizes, int n_in,
                              void* d_out, int out_size, void* d_ws, size_t ws_size,
                              hipStream_t stream)
{
    const float* X = (const float*)d_in[0];   // (32768, 1280) fp32
    const float* E = (const float*)d_in[1];   // (4096, 1280) fp32

    float* outq = (float*)d_out;                       // (32768,1280)
    float* outidx = outq + (size_t)N_TOKENS * DIM;     // (32768,) as float
    float* outloss = outidx + N_TOKENS;                // scalar

    // i8 temps + scales inside outq region (47.3 MB of 167.9 MB); consumed
    // by GEMM, then fully overwritten by refine_gather in-stream.
    signed char* Xq = (signed char*)d_out;                        // 41.9 MB
    signed char* Eq = Xq + (size_t)N_TOKENS * DIM;                // 5.2 MB
    float* sxs = (float*)(Eq + (size_t)N_CODES * DIM);            // 128 KB
    float* ses = sxs + N_TOKENS;                                  // 16 KB

    unsigned* pkeys = (unsigned*)d_ws;                            // 8 MB
    float* sums = (float*)((char*)d_ws + (size_t)N_TOKENS * 64 * sizeof(unsigned));

    quantize_i8_kernel<<<dim3(N_TOKENS / 4), dim3(256), 0, stream>>>(X, Xq, sxs, N_TOKENS);
    quantize_i8_kernel<<<dim3(N_CODES / 4), dim3(256), 0, stream>>>(E, Eq, ses, N_CODES);
    gemm_argmax_kernel<<<dim3(2048), dim3(512), 0, stream>>>(Xq, Eq, sxs, ses, pkeys);
    refine_gather_kernel<<<dim3(N_TOKENS), dim3(64), 0, stream>>>(X, E, pkeys, outq, outidx, sums);
    loss_kernel<<<dim3(1), dim3(256), 0, stream>>>(sums, outloss);
}

// Round 6
// 380.563 us; speedup vs baseline: 3.8640x; 1.1506x over previous
//
#include <hip/hip_runtime.h>
#include <hip/hip_bf16.h>

typedef int i32x4 __attribute__((ext_vector_type(4)));

#define N_TOKENS 32768
#define N_CODES 4096
#define DIM 1280
#define NT 20            // K-tiles of 64 (i8)
#define BUFSZ 32768      // A 16KB + B 16KB per K-tile buffer

__device__ __forceinline__ void load_lds16(const void* g, void* l) {
    __builtin_amdgcn_global_load_lds(
        (const __attribute__((address_space(1))) unsigned int*)g,
        (__attribute__((address_space(3))) unsigned int*)l,
        16, 0, 0);
}

// ---------------------------------------------------------------------------
// Kernel 0: per-row symmetric int8 quantize (RNE). Verified round 5.
// ---------------------------------------------------------------------------
__global__ __launch_bounds__(256) void quantize_i8_kernel(
    const float* __restrict__ src, signed char* __restrict__ dst,
    float* __restrict__ scale, int nrows)
{
    int row = blockIdx.x * 4 + (threadIdx.x >> 6);
    if (row >= nrows) return;
    int lane = threadIdx.x & 63;
    const float4* s4 = (const float4*)(src + (size_t)row * DIM);
    float4 v[5];
    float amax = 0.f;
    #pragma unroll
    for (int j = 0; j < 5; ++j) {
        v[j] = s4[j * 64 + lane];
        amax = fmaxf(amax, fmaxf(fmaxf(fabsf(v[j].x), fabsf(v[j].y)),
                                 fmaxf(fabsf(v[j].z), fabsf(v[j].w))));
    }
    #pragma unroll
    for (int d = 1; d < 64; d <<= 1) amax = fmaxf(amax, __shfl_xor(amax, d));
    amax = fmaxf(amax, 1e-20f);
    float inv = 127.0f / amax;
    int* d4 = (int*)(dst + (size_t)row * DIM);
    #pragma unroll
    for (int j = 0; j < 5; ++j) {
        int q0 = (int)rintf(v[j].x * inv), q1 = (int)rintf(v[j].y * inv);
        int q2 = (int)rintf(v[j].z * inv), q3 = (int)rintf(v[j].w * inv);
        d4[j * 64 + lane] = (q0 & 0xFF) | ((q1 & 0xFF) << 8) |
                            ((q2 & 0xFF) << 16) | ((q3 & 0xFF) << 24);
    }
    if (lane == 0) scale[row] = amax * (1.0f / 127.0f);
}

// ---------------------------------------------------------------------------
// Kernel 1: i8 GEMM 256x256 tile, 16 waves (4x4 wave grid, wave tile 64x64),
// BK=64, mfma_i32_16x16x64_i8. Round-4/5 ledger, re-counted for 2 loads per
// thread per STAGE: prologue 3 stages = 6 outstanding, vmcnt(4) => tile t+1
// complete; in-loop after STAGE(t+3) outstanding=6, vmcnt(4) => t+1 done;
// tail vmcnt(2)/vmcnt(0). Overwrite: STAGE(t+3) writes buf[(t+3)&3], last
// read iter t-1 before its end barrier => safe.
// acc = 4x4 i32x4 = 64 regs => ~120 total => 4 waves/SIMD (the round-5
// bottleneck was 244 unified regs => 2 waves/SIMD).
// LDS layout identical to r4/r5: paired rows (2 rows per 128B LDS row),
// 16B chunk c of pair rp holds source chunk c^(rp&7) (both-sides swizzle).
// ---------------------------------------------------------------------------
__global__ __launch_bounds__(1024, 4) void gemm_argmax_kernel(
    const signed char* __restrict__ Xq, const signed char* __restrict__ Eq,
    const float* __restrict__ sx, const float* __restrict__ se,
    unsigned* __restrict__ pkeys)
{
    __shared__ __align__(16) char lds[4 * BUFSZ];   // 128 KB

    int bid = blockIdx.x;
    // bijective XCD swizzle, cb0-major within XCD (B-panel stays in L2)
    int swz = (bid & 7) * 256 + (bid >> 3);
    int cb0 = swz >> 7, rb = swz & 127;
    int row0 = rb << 8, col0 = cb0 << 8;

    int tid = threadIdx.x;
    int wid = tid >> 6, lane = tid & 63;
    int wm = wid >> 2, wn = wid & 3;        // 4x4 wave grid
    int lr = lane & 15, g = lane >> 4;

    // per-lane constant swizzled fragment offsets; row bases are multiples
    // of 16 so rp&7 == (lr>>1)&7 for every fragment row.
    int slot = (((lr & 1) << 2) + g) ^ ((lr >> 1) & 7);
    int aoff = ((wm << 5) + (lr >> 1)) * 128 + slot * 16;            // A region
    int boff = 16384 + ((wn << 5) + (lr >> 1)) * 128 + slot * 16;    // B region

    i32x4 acc[4][4] = {};

    auto STAGE = [&](int t) {
        int base = (t & 3) * BUFSZ;
        int k0 = t << 6;                     // byte offset in row (i8)
        int f = tid;                         // slot 0..1023
        int rp = f >> 3, c = f & 7;
        int cp = c ^ (rp & 7);               // pre-swizzled source chunk
        int gr = (rp << 1) + (cp >> 2);      // global row in tile
        int kc = k0 + ((cp & 3) << 4);       // 16B k-chunk
        load_lds16(Xq + (size_t)(row0 + gr) * DIM + kc, lds + base + (f << 4));
        load_lds16(Eq + (size_t)(col0 + gr) * DIM + kc, lds + base + 16384 + (f << 4));
    };

    auto COMPUTE = [&](int t) {
        int base = (t & 3) * BUFSZ;
        const char* pA = lds + base + aoff;
        const char* pB = lds + base + boff;
        i32x4 a[4], b[4];
        #pragma unroll
        for (int m = 0; m < 4; ++m) a[m] = *(const i32x4*)(pA + (m << 10));
        #pragma unroll
        for (int n = 0; n < 4; ++n) b[n] = *(const i32x4*)(pB + (n << 10));
        __builtin_amdgcn_s_setprio(1);
        #pragma unroll
        for (int m = 0; m < 4; ++m)
            #pragma unroll
            for (int n = 0; n < 4; ++n)
                acc[m][n] = __builtin_amdgcn_mfma_i32_16x16x64_i8(
                    a[m], b[n], acc[m][n], 0, 0, 0);
        __builtin_amdgcn_s_setprio(0);
    };

    STAGE(0); STAGE(1); STAGE(2);                 // 6 outstanding
    asm volatile("s_waitcnt vmcnt(4)" ::: "memory");
    __builtin_amdgcn_s_barrier();
    __builtin_amdgcn_sched_barrier(0);

    for (int t = 0; t < NT - 3; ++t) {
        STAGE(t + 3);
        COMPUTE(t);
        asm volatile("s_waitcnt vmcnt(4)" ::: "memory");
        __builtin_amdgcn_s_barrier();
        __builtin_amdgcn_sched_barrier(0);
    }
    COMPUTE(NT - 3);
    asm volatile("s_waitcnt vmcnt(2)" ::: "memory");
    __builtin_amdgcn_s_barrier();
    __builtin_amdgcn_sched_barrier(0);
    COMPUTE(NT - 2);
    asm volatile("s_waitcnt vmcnt(0)" ::: "memory");
    __builtin_amdgcn_s_barrier();
    __builtin_amdgcn_sched_barrier(0);
    COMPUTE(NT - 1);
    __syncthreads();   // full drain; LDS reused for epilogue merge

    // ---- dequant + fused top-2 argmax epilogue ----
    // C/D frag layout (dtype-independent): col = lr, row = g*4 + r.
    float se_l[4];
    #pragma unroll
    for (int n = 0; n < 4; ++n)
        se_l[n] = se[col0 + (wn << 6) + (n << 4) + lr];

    uint2* lk2 = (uint2*)lds;   // [256 rows][4 wn]
    #pragma unroll
    for (int m = 0; m < 4; ++m) {
        #pragma unroll
        for (int r = 0; r < 4; ++r) {
            int row = (wm << 6) + (m << 4) + (g << 2) + r;
            float fx = sx[row0 + row];
            unsigned b1 = 0, b2 = 0;
            #pragma unroll
            for (int n = 0; n < 4; ++n) {
                float s = (float)acc[m][n][r] * (fx * se_l[n]);
                int cib = ((wn & 1) << 6) + (n << 4) + lr;   // col in 128-block
                unsigned u = __float_as_uint(s);
                u = (u & 0x80000000u) ? ~u : (u | 0x80000000u);
                unsigned key = (u & 0xFFFFFF80u) | (unsigned)(127 - cib);
                if (key > b1) { b2 = b1; b1 = key; }
                else if (key > b2) b2 = key;
            }
            #pragma unroll
            for (int d = 1; d < 16; d <<= 1) {   // merge across 16 lanes (lr)
                unsigned o1 = __shfl_xor(b1, d), o2 = __shfl_xor(b2, d);
                if (o1 > b1) { b2 = (b1 > o2) ? b1 : o2; b1 = o1; }
                else if (o1 > b2) b2 = o1;
            }
            if (lr == 0) {
                uint2 v; v.x = b1; v.y = b2;
                lk2[(row << 2) + wn] = v;
            }
        }
    }
    __syncthreads();
    if (tid < 512) {
        // wn {0,1} -> col-block half h=0; wn {2,3} -> h=1
        int row = tid >> 1, h = tid & 1;
        uint2 p0 = lk2[(row << 2) + (h << 1)];
        uint2 p1 = lk2[(row << 2) + (h << 1) + 1];
        unsigned b1 = p0.x, b2 = p0.y;
        if (p1.x > b1) { b2 = (b1 > p1.y) ? b1 : p1.y; b1 = p1.x; }
        else if (p1.x > b2) b2 = p1.x;
        uint2 out; out.x = b1; out.y = b2;
        *(uint2*)&pkeys[((size_t)(row0 + row) << 6) + (((cb0 << 1) + h) << 1)] = out;
    }
}

// ---------------------------------------------------------------------------
// Kernel 2: fused exact fp64 refine + gather + loss partial. One wave/token.
// X loaded ONCE as float4 and reused for both the fp64 dot and the gather
// diff (round-5 version read X twice). Threshold 3e-3 (~9 sigma i8 noise).
// ---------------------------------------------------------------------------
__global__ __launch_bounds__(64) void refine_gather_kernel(
    const float* __restrict__ X, const float* __restrict__ E,
    const unsigned* __restrict__ pkeys, float* __restrict__ outq,
    float* __restrict__ outidx, float* __restrict__ sums)
{
    int token = blockIdx.x;
    int lane = threadIdx.x;
    unsigned k = pkeys[((size_t)token << 6) + lane];
    unsigned m = k & 0xFFFFFF80u;
    float s = __uint_as_float((m & 0x80000000u) ? (m & 0x7FFFFFFFu) : ~m);
    float smax = s;
    #pragma unroll
    for (int d = 1; d < 64; d <<= 1) smax = fmaxf(smax, __shfl_xor(smax, d));
    bool cand = s >= smax - 3e-3f;
    unsigned long long ball = __ballot(cand);

    const float4* x4 = (const float4*)(X + (size_t)token * DIM);
    float4 xv[5];
    #pragma unroll
    for (int j = 0; j < 5; ++j) xv[j] = x4[j * 64 + lane];

    double best_s = -1.0e300;
    int best_i = 0x7FFFFFFF;
    while (ball) {
        int src = __ffsll(ball) - 1;
        ball &= ball - 1;
        unsigned ck = __shfl(k, src);
        int cidx = ((src >> 1) << 7) + (127 - (int)(ck & 127u));
        const float4* e4 = (const float4*)(E + (size_t)cidx * DIM);
        double d = 0.0, ee = 0.0;
        #pragma unroll
        for (int j = 0; j < 5; ++j) {
            float4 ev = e4[j * 64 + lane];
            d += (double)xv[j].x * (double)ev.x + (double)xv[j].y * (double)ev.y
               + (double)xv[j].z * (double)ev.z + (double)xv[j].w * (double)ev.w;
            ee += (double)ev.x * (double)ev.x + (double)ev.y * (double)ev.y
                + (double)ev.z * (double)ev.z + (double)ev.w * (double)ev.w;
        }
        #pragma unroll
        for (int dd = 1; dd < 64; dd <<= 1) {
            d += __shfl_xor(d, dd);
            ee += __shfl_xor(ee, dd);
        }
        double sc = 2.0 * d - ee;
        if (sc > best_s || (sc == best_s && cidx < best_i)) { best_s = sc; best_i = cidx; }
    }

    // gather + commit-loss partial (reuses xv)
    const float4* e4 = (const float4*)(E + (size_t)best_i * DIM);
    float4* o4 = (float4*)(outq + (size_t)token * DIM);
    float local = 0.0f;
    #pragma unroll
    for (int j = 0; j < 5; ++j) {
        float4 q = e4[j * 64 + lane];
        o4[j * 64 + lane] = q;
        float dx = xv[j].x - q.x, dy = xv[j].y - q.y;
        float dz = xv[j].z - q.z, dw = xv[j].w - q.w;
        local += dx * dx + dy * dy + dz * dz + dw * dw;
    }
    #pragma unroll
    for (int d = 1; d < 64; d <<= 1) local += __shfl_xor(local, d);
    if (lane == 0) {
        sums[token] = local;
        outidx[token] = (float)best_i;
    }
}

// ---------------------------------------------------------------------------
// Kernel 3: deterministic final loss reduction (fixed tree).
// ---------------------------------------------------------------------------
__global__ __launch_bounds__(256) void loss_kernel(
    const float* __restrict__ sums, float* __restrict__ out_loss)
{
    __shared__ double red[256];
    int t = threadIdx.x;
    double s = 0.0;
    for (int i = t; i < N_TOKENS; i += 256) s += (double)sums[i];
    red[t] = s;
    __syncthreads();
    for (int off = 128; off > 0; off >>= 1) {
        if (t < off) red[t] += red[t + off];
        __syncthreads();
    }
    if (t == 0) out_loss[0] = (float)(red[0] / (double)((size_t)N_TOKENS * DIM));
}

extern "C" void kernel_launch(void* const* d_in, const int* in_sizes, int n_in,
                              void* d_out, int out_size, void* d_ws, size_t ws_size,
                              hipStream_t stream)
{
    const float* X = (const float*)d_in[0];   // (32768, 1280) fp32
    const float* E = (const float*)d_in[1];   // (4096, 1280) fp32

    float* outq = (float*)d_out;                       // (32768,1280)
    float* outidx = outq + (size_t)N_TOKENS * DIM;     // (32768,) as float
    float* outloss = outidx + N_TOKENS;                // scalar

    // i8 temps + scales inside outq region (47.3 MB of 167.9 MB); consumed
    // by GEMM, then fully overwritten by refine_gather in-stream.
    signed char* Xq = (signed char*)d_out;                        // 41.9 MB
    signed char* Eq = Xq + (size_t)N_TOKENS * DIM;                // 5.2 MB
    float* sxs = (float*)(Eq + (size_t)N_CODES * DIM);            // 128 KB
    float* ses = sxs + N_TOKENS;                                  // 16 KB

    unsigned* pkeys = (unsigned*)d_ws;                            // 8 MB
    float* sums = (float*)((char*)d_ws + (size_t)N_TOKENS * 64 * sizeof(unsigned));

    quantize_i8_kernel<<<dim3(N_TOKENS / 4), dim3(256), 0, stream>>>(X, Xq, sxs, N_TOKENS);
    quantize_i8_kernel<<<dim3(N_CODES / 4), dim3(256), 0, stream>>>(E, Eq, ses, N_CODES);
    gemm_argmax_kernel<<<dim3(2048), dim3(1024), 0, stream>>>(Xq, Eq, sxs, ses, pkeys);
    refine_gather_kernel<<<dim3(N_TOKENS), dim3(64), 0, stream>>>(X, E, pkeys, outq, outidx, sums);
    loss_kernel<<<dim3(1), dim3(256), 0, stream>>>(sums, outloss);
}